// Round 1
// baseline (404.352 us; speedup 1.0000x reference)
//
#include <hip/hip_runtime.h>
#include <math.h>

// Problem constants (b, n, m) = (16, 2048, 2048); scores is (16, 2049, 2049) fp32.
#define BATCH 16
#define NN 2048
#define MM 2048
#define WW 2049
#define RPB 32          // rows per block (8 per wave, 4 waves)
#define NCHUNK 65       // ceil(2049/32)

// --- Kernel 1: gather pos0[b,i] = scores[b,i,gt0[b,i]], pos1[b,j] = scores[b,gt1[b,j],j]
__global__ __launch_bounds__(256) void gather_kernel(
    const float* __restrict__ scores, const int* __restrict__ gt0,
    const int* __restrict__ gt1, float* __restrict__ pos0, float* __restrict__ pos1)
{
    int id = blockIdx.x * 256 + threadIdx.x;
    const int half = BATCH * NN;
    if (id < half) {
        int b = id >> 11, i = id & (NN - 1);
        int g = gt0[id];
        g = (g == -1) ? MM : g;
        g = min(max(g, 0), MM);
        pos0[id] = scores[(size_t)b * WW * WW + (size_t)i * WW + g];
    } else {
        int id2 = id - half;
        int b = id2 >> 11, j = id2 & (MM - 1);
        int g = gt1[id2];
        g = (g == -1) ? NN : g;
        g = min(max(g, 0), NN);
        pos1[id2] = scores[(size_t)b * WW * WW + (size_t)g * WW + j];
    }
}

// --- Kernel 2: single pass over scores. Row sums (wave-reduced, log'd, atomic to
// rowacc[b]) and column partial sums (register acc -> LDS combine -> global atomic).
__global__ __launch_bounds__(256) void main_kernel(
    const float* __restrict__ scores, const float* __restrict__ pos0,
    const float* __restrict__ pos1, float* __restrict__ colsum,
    float* __restrict__ rowacc)
{
    const int b = blockIdx.y;
    const int row0 = blockIdx.x * RPB;
    const int tid = threadIdx.x;
    const int wave = tid >> 6;
    const int lane = tid & 63;

    const float* sb = scores + (size_t)b * WW * WW;
    const float* p1b = pos1 + b * MM;

    float pos1v[32];
    float colacc[32];
#pragma unroll
    for (int k = 0; k < 32; ++k) {
        pos1v[k] = p1b[lane + 64 * k];   // column j = lane + 64k  (j < 2048)
        colacc[k] = 0.0f;
    }

    float rowterm = 0.0f;   // per-wave accumulated 2*log(rowsum+0.5), lane 0 only
    for (int r = wave; r < RPB; r += 4) {
        const int i = row0 + r;
        if (i >= WW) break;                    // wave-uniform; no barriers inside loop
        const bool has_row = (i < NN);
        const float p0 = has_row ? pos0[b * NN + i] : 0.0f;
        const float* rowp = sb + (size_t)i * WW;

        float rowpart = 0.0f;
#pragma unroll
        for (int k = 0; k < 32; ++k) {
            const float s = rowp[lane + 64 * k] + 0.5f;   // s + gamma
            rowpart += fmaxf(s - p0, 0.0f);               // row contribution (j<2049, here j<2048)
            colacc[k] += fmaxf(s - pos1v[k], 0.0f);       // col contribution (all i in [0,2049))
        }
        if (has_row) {
            if (lane == 0)                                 // j == 2048 column (row-only)
                rowpart += fmaxf(rowp[2048] + 0.5f - p0, 0.0f);
#pragma unroll
            for (int off = 32; off; off >>= 1)
                rowpart += __shfl_xor(rowpart, off);
            if (lane == 0)
                rowterm += 2.0f * logf(rowpart + 0.5f);    // log(sum - gamma + 1)
        }
    }
    if (lane == 0)
        unsafeAtomicAdd(&rowacc[b], rowterm);

    // Combine per-wave column partials in LDS (phased, deterministic, conflict-free).
    __shared__ float cl[MM];
    for (int j = tid; j < MM; j += 256) cl[j] = 0.0f;
    __syncthreads();
    for (int w = 0; w < 4; ++w) {
        if (wave == w) {
#pragma unroll
            for (int k = 0; k < 32; ++k) cl[lane + 64 * k] += colacc[k];
        }
        __syncthreads();
    }
    for (int j = tid; j < MM; j += 256)
        unsafeAtomicAdd(&colsum[b * MM + j], cl[j]);
}

// --- Kernel 3: per-batch finalize. out[b] = 0.5*(rowacc/n + sum_j 2log(colsum+0.5)/m)
__global__ __launch_bounds__(256) void finalize_kernel(
    const float* __restrict__ colsum, const float* __restrict__ rowacc,
    float* __restrict__ out)
{
    const int b = blockIdx.x;
    const int tid = threadIdx.x;
    const int wave = tid >> 6;
    const int lane = tid & 63;

    float acc = 0.0f;
    for (int j = tid; j < MM; j += 256)
        acc += 2.0f * logf(colsum[b * MM + j] + 0.5f);

#pragma unroll
    for (int off = 32; off; off >>= 1)
        acc += __shfl_xor(acc, off);

    __shared__ float red[4];
    if (lane == 0) red[wave] = acc;
    __syncthreads();
    if (tid == 0) {
        const float colterms = red[0] + red[1] + red[2] + red[3];
        out[b] = 0.5f * (rowacc[b] * (1.0f / NN) + colterms * (1.0f / MM));
    }
}

extern "C" void kernel_launch(void* const* d_in, const int* in_sizes, int n_in,
                              void* d_out, int out_size, void* d_ws, size_t ws_size,
                              hipStream_t stream) {
    const int* gt0 = (const int*)d_in[0];
    const int* gt1 = (const int*)d_in[1];
    const float* scores = (const float*)d_in[2];
    float* out = (float*)d_out;

    float* ws = (float*)d_ws;
    float* pos0   = ws;                       // BATCH*NN floats
    float* pos1   = ws + (size_t)BATCH * NN;  // BATCH*MM floats
    float* colsum = ws + (size_t)2 * BATCH * NN; // BATCH*MM floats
    float* rowacc = ws + (size_t)3 * BATCH * NN; // BATCH floats

    // zero the accumulators (ws is re-poisoned to 0xAA before every launch)
    hipMemsetAsync(colsum, 0, ((size_t)BATCH * MM + BATCH) * sizeof(float), stream);

    gather_kernel<<<(2 * BATCH * NN) / 256, 256, 0, stream>>>(scores, gt0, gt1, pos0, pos1);

    dim3 grid(NCHUNK, BATCH);
    main_kernel<<<grid, 256, 0, stream>>>(scores, pos0, pos1, colsum, rowacc);

    finalize_kernel<<<BATCH, 256, 0, stream>>>(colsum, rowacc, out);
}

// Round 2
// 392.067 us; speedup vs baseline: 1.0313x; 1.0313x over previous
//
#include <hip/hip_runtime.h>
#include <math.h>

// Problem constants (b, n, m) = (16, 2048, 2048); scores is (16, 2049, 2049) fp32.
#define BATCH 16
#define NN 2048
#define MM 2048
#define WW 2049
#define GAMMA 0.5f

// --- Kernel 1: gather q0[b,i] = scores[b,i,gt0[b,i]] - GAMMA,
//               q1[b,j] = scores[b,gt1[b,j],j] - GAMMA.
// Folding gamma here lets the main pass use  max(s-q,0) = max(s,q) - q,
// accumulating only max(s,q) (2 VALU/elem/side) and subtracting 2049*q at the end.
__global__ __launch_bounds__(256) void gather_kernel(
    const float* __restrict__ scores, const int* __restrict__ gt0,
    const int* __restrict__ gt1, float* __restrict__ q0, float* __restrict__ q1)
{
    int id = blockIdx.x * 256 + threadIdx.x;
    const int half = BATCH * NN;
    if (id < half) {
        int b = id >> 11, i = id & (NN - 1);
        int g = gt0[id];
        g = (g == -1) ? MM : g;
        g = min(max(g, 0), MM);
        q0[id] = scores[(size_t)b * WW * WW + (size_t)i * WW + g] - GAMMA;
    } else {
        int id2 = id - half;
        int b = id2 >> 11, j = id2 & (MM - 1);
        int g = gt1[id2];
        g = (g == -1) ? NN : g;
        g = min(max(g, 0), NN);
        q1[id2] = scores[(size_t)b * WW * WW + (size_t)g * WW + j] - GAMMA;
    }
}

// --- Kernel 2: single pass over scores.
// Row i term:  2*log( sum_j max(s,q0_i) - 2049*q0_i + 0.5 )   (j in [0,2049))
// Col j accum: colsum[b,j] += sum_i max(s,q1_j)               (i in [0,2049), j < 2048)
// Grid 64x16 = 1024 blocks = exactly 4/CU (no tail); block x=63 takes 33 rows.
__global__ __launch_bounds__(256) void main_kernel(
    const float* __restrict__ scores, const float* __restrict__ q0,
    const float* __restrict__ q1, float* __restrict__ colsum,
    float* __restrict__ rowacc)
{
    const int b = blockIdx.y;
    const int row0 = blockIdx.x * 32;
    const int nrows = (blockIdx.x == 63) ? 33 : 32;   // fold row 2048 into last chunk
    const int tid = threadIdx.x;
    const int wave = tid >> 6;
    const int lane = tid & 63;

    const float* sb = scores + (size_t)b * WW * WW;
    const float* q1b = q1 + b * MM;

    float q1v[32];
    float colacc[32];
#pragma unroll
    for (int k = 0; k < 32; ++k) {
        q1v[k] = q1b[lane + 64 * k];   // column j = lane + 64k  (j < 2048)
        colacc[k] = 0.0f;
    }

    float rowterm = 0.0f;   // lane-0 accumulated 2*log(rowsum+0.5)
    for (int r = wave; r < nrows; r += 4) {
        const int i = row0 + r;
        const bool has_row = (i < NN);                 // i == 2048: col-only row
        const float q0i = has_row ? q0[b * NN + i] : 0.0f;
        const float* rowp = sb + (size_t)i * WW;

        float rp = 0.0f;
#pragma unroll
        for (int k = 0; k < 32; ++k) {
            const float s = rowp[lane + 64 * k];
            rp += fmaxf(s, q0i);                       // row contribution
            colacc[k] = fmaxf(s, q1v[k]) + colacc[k];  // col contribution
        }
        if (has_row) {
            if (lane == 0)                             // j == 2048 column (row-only)
                rp += fmaxf(rowp[2048], q0i);
#pragma unroll
            for (int off = 32; off; off >>= 1)
                rp += __shfl_xor(rp, off);
            if (lane == 0)
                rowterm += 2.0f * logf(rp - 2049.0f * q0i + 0.5f);
        }
    }
    if (lane == 0)
        unsafeAtomicAdd(&rowacc[b], rowterm);

    // Per-wave colacc -> LDS slabs (conflict-free), one barrier, 4-way sum, one
    // global atomic per column per block.
    __shared__ float cl[4][MM];
#pragma unroll
    for (int k = 0; k < 32; ++k)
        cl[wave][lane + 64 * k] = colacc[k];
    __syncthreads();
    for (int j = tid; j < MM; j += 256) {
        const float v = cl[0][j] + cl[1][j] + cl[2][j] + cl[3][j];
        unsafeAtomicAdd(&colsum[b * MM + j], v);
    }
}

// --- Kernel 3: per-batch finalize.
// out[b] = 0.5*( rowacc[b]/n + (1/m) * sum_j 2*log(colsum[b,j] - 2049*q1[b,j] + 0.5) )
__global__ __launch_bounds__(256) void finalize_kernel(
    const float* __restrict__ colsum, const float* __restrict__ q1,
    const float* __restrict__ rowacc, float* __restrict__ out)
{
    const int b = blockIdx.x;
    const int tid = threadIdx.x;
    const int wave = tid >> 6;
    const int lane = tid & 63;

    float acc = 0.0f;
    for (int j = tid; j < MM; j += 256) {
        const float cs = colsum[b * MM + j] - 2049.0f * q1[b * MM + j];
        acc += 2.0f * logf(cs + 0.5f);
    }

#pragma unroll
    for (int off = 32; off; off >>= 1)
        acc += __shfl_xor(acc, off);

    __shared__ float red[4];
    if (lane == 0) red[wave] = acc;
    __syncthreads();
    if (tid == 0) {
        const float colterms = red[0] + red[1] + red[2] + red[3];
        out[b] = 0.5f * (rowacc[b] * (1.0f / NN) + colterms * (1.0f / MM));
    }
}

extern "C" void kernel_launch(void* const* d_in, const int* in_sizes, int n_in,
                              void* d_out, int out_size, void* d_ws, size_t ws_size,
                              hipStream_t stream) {
    const int* gt0 = (const int*)d_in[0];
    const int* gt1 = (const int*)d_in[1];
    const float* scores = (const float*)d_in[2];
    float* out = (float*)d_out;

    float* ws = (float*)d_ws;
    float* q0     = ws;                           // BATCH*NN floats
    float* q1     = ws + (size_t)BATCH * NN;      // BATCH*MM floats
    float* colsum = ws + (size_t)2 * BATCH * NN;  // BATCH*MM floats
    float* rowacc = ws + (size_t)3 * BATCH * NN;  // BATCH floats

    // zero the accumulators (ws is re-poisoned to 0xAA before every launch)
    hipMemsetAsync(colsum, 0, ((size_t)BATCH * MM + BATCH) * sizeof(float), stream);

    gather_kernel<<<(2 * BATCH * NN) / 256, 256, 0, stream>>>(scores, gt0, gt1, q0, q1);

    dim3 grid(64, BATCH);
    main_kernel<<<grid, 256, 0, stream>>>(scores, q0, q1, colsum, rowacc);

    finalize_kernel<<<BATCH, 256, 0, stream>>>(colsum, q1, rowacc, out);
}

// Round 3
// 386.728 us; speedup vs baseline: 1.0456x; 1.0138x over previous
//
#include <hip/hip_runtime.h>
#include <math.h>

// Problem constants (b, n, m) = (16, 2048, 2048); scores is (16, 2049, 2049) fp32.
#define BATCH 16
#define NN 2048
#define MM 2048
#define WW 2049
#define GAMMA 0.5f
#define NBX 64          // row-chunks per batch (32 rows each; last takes 33)

// ws layout (floats):
//   q0      : BATCH*NN                  (32768)
//   q1      : BATCH*MM                  (32768)
//   colpart : NBX*BATCH*MM              (2097152 = 8 MB)
//   rowpart : NBX*BATCH                 (1024)
//   colterm : BATCH*8                   (128)
// No global atomics anywhere; every slot is written unconditionally each call.

// --- Kernel 1: gather q0[b,i] = scores[b,i,gt0[b,i]] - GAMMA,
//               q1[b,j] = scores[b,gt1[b,j],j] - GAMMA.
// max(s-q+GAMMA, 0) = max(s, q) - q with q = pos - GAMMA; the -q correction is
// applied once per row/column at the log step (2049 elements per sum).
__global__ __launch_bounds__(256) void gather_kernel(
    const float* __restrict__ scores, const int* __restrict__ gt0,
    const int* __restrict__ gt1, float* __restrict__ q0, float* __restrict__ q1)
{
    int id = blockIdx.x * 256 + threadIdx.x;
    const int half = BATCH * NN;
    if (id < half) {
        int b = id >> 11, i = id & (NN - 1);
        int g = gt0[id];
        g = (g == -1) ? MM : g;
        g = min(max(g, 0), MM);
        q0[id] = scores[(size_t)b * WW * WW + (size_t)i * WW + g] - GAMMA;
    } else {
        int id2 = id - half;
        int b = id2 >> 11, j = id2 & (MM - 1);
        int g = gt1[id2];
        g = (g == -1) ? NN : g;
        g = min(max(g, 0), NN);
        q1[id2] = scores[(size_t)b * WW * WW + (size_t)g * WW + j] - GAMMA;
    }
}

// --- Kernel 2: single pass over scores.
// Row i term:  2*log( sum_j max(s,q0_i) - 2049*q0_i + 0.5 )  accumulated per block
// Col j accum: colpart[bx][b][j] = block's partial of sum_i max(s,q1_j)
// Grid 64x16 = 1024 blocks = exactly 4/CU; block x=63 takes 33 rows (row 2048 is
// column-only). No atomics: each block owns a private colpart/rowpart slot.
__global__ __launch_bounds__(256) void main_kernel(
    const float* __restrict__ scores, const float* __restrict__ q0,
    const float* __restrict__ q1, float* __restrict__ colpart,
    float* __restrict__ rowpart)
{
    const int b = blockIdx.y;
    const int row0 = blockIdx.x * 32;
    const int nrows = (blockIdx.x == 63) ? 33 : 32;
    const int tid = threadIdx.x;
    const int wave = tid >> 6;
    const int lane = tid & 63;

    const float* sb = scores + (size_t)b * WW * WW;
    const float* q1b = q1 + b * MM;

    float q1v[32];
    float colacc[32];
#pragma unroll
    for (int k = 0; k < 32; ++k) {
        q1v[k] = q1b[lane + 64 * k];   // column j = lane + 64k (j < 2048)
        colacc[k] = 0.0f;
    }

    float rowterm = 0.0f;   // lane-0 accumulated 2*log(rowsum+0.5)
    for (int r = wave; r < nrows; r += 4) {
        const int i = row0 + r;
        const bool has_row = (i < NN);                 // i == 2048: col-only row
        const float q0i = has_row ? q0[b * NN + i] : 0.0f;
        const float* rowp = sb + (size_t)i * WW;

        float rp = 0.0f;
#pragma unroll
        for (int k = 0; k < 32; ++k) {
            const float s = rowp[lane + 64 * k];
            rp += fmaxf(s, q0i);                       // row contribution
            colacc[k] = fmaxf(s, q1v[k]) + colacc[k];  // col contribution
        }
        if (has_row) {
            if (lane == 0)                             // j == 2048 column (row-only)
                rp += fmaxf(rowp[2048], q0i);
#pragma unroll
            for (int off = 32; off; off >>= 1)
                rp += __shfl_xor(rp, off);
            if (lane == 0)
                rowterm += 2.0f * logf(rp - 2049.0f * q0i + 0.5f);
        }
    }

    // Per-wave colacc -> LDS slabs (2-way bank alias only), one barrier, 4-way
    // sum, plain coalesced store to this block's private colpart slice.
    __shared__ float cl[4][MM];
    __shared__ float rw[4];
#pragma unroll
    for (int k = 0; k < 32; ++k)
        cl[wave][lane + 64 * k] = colacc[k];
    if (lane == 0) rw[wave] = rowterm;
    __syncthreads();

    float* dst = colpart + ((size_t)blockIdx.x * BATCH + b) * MM;
    for (int j = tid; j < MM; j += 256)
        dst[j] = cl[0][j] + cl[1][j] + cl[2][j] + cl[3][j];
    if (tid == 0)
        rowpart[blockIdx.x * BATCH + b] = rw[0] + rw[1] + rw[2] + rw[3];
}

// --- Kernel 3: per-(b, 256-col chunk) reduce of the 64 block partials, then
// the log term, block-reduced into colterm[b*8 + jc]. Grid (8, 16), 256 thr.
__global__ __launch_bounds__(256) void reduce_cols_kernel(
    const float* __restrict__ colpart, const float* __restrict__ q1,
    float* __restrict__ colterm)
{
    const int b = blockIdx.y;
    const int j = blockIdx.x * 256 + threadIdx.x;
    const int tid = threadIdx.x;
    const int wave = tid >> 6;
    const int lane = tid & 63;

    float s0 = 0.0f, s1 = 0.0f, s2 = 0.0f, s3 = 0.0f;
#pragma unroll
    for (int bx = 0; bx < NBX; bx += 4) {
        s0 += colpart[((size_t)(bx + 0) * BATCH + b) * MM + j];
        s1 += colpart[((size_t)(bx + 1) * BATCH + b) * MM + j];
        s2 += colpart[((size_t)(bx + 2) * BATCH + b) * MM + j];
        s3 += colpart[((size_t)(bx + 3) * BATCH + b) * MM + j];
    }
    const float cs = (s0 + s1) + (s2 + s3);
    float term = 2.0f * logf(cs - 2049.0f * q1[b * MM + j] + 0.5f);

#pragma unroll
    for (int off = 32; off; off >>= 1)
        term += __shfl_xor(term, off);

    __shared__ float red[4];
    if (lane == 0) red[wave] = term;
    __syncthreads();
    if (tid == 0)
        colterm[b * 8 + blockIdx.x] = red[0] + red[1] + red[2] + red[3];
}

// --- Kernel 4: final combine. 16 blocks x 64 threads.
// out[b] = 0.5*( sum_bx rowpart[bx][b]/n + sum_jc colterm[b][jc]/m )
__global__ __launch_bounds__(64) void final_kernel(
    const float* __restrict__ rowpart, const float* __restrict__ colterm,
    float* __restrict__ out)
{
    const int b = blockIdx.x;
    const int lane = threadIdx.x;

    float rs = rowpart[lane * BATCH + b];            // 64 row-chunk partials
    float cs = (lane < 8) ? colterm[b * 8 + lane] : 0.0f;
#pragma unroll
    for (int off = 32; off; off >>= 1) {
        rs += __shfl_xor(rs, off);
        cs += __shfl_xor(cs, off);
    }
    if (lane == 0)
        out[b] = 0.5f * (rs * (1.0f / NN) + cs * (1.0f / MM));
}

extern "C" void kernel_launch(void* const* d_in, const int* in_sizes, int n_in,
                              void* d_out, int out_size, void* d_ws, size_t ws_size,
                              hipStream_t stream) {
    const int* gt0 = (const int*)d_in[0];
    const int* gt1 = (const int*)d_in[1];
    const float* scores = (const float*)d_in[2];
    float* out = (float*)d_out;

    float* ws = (float*)d_ws;
    float* q0      = ws;
    float* q1      = q0 + (size_t)BATCH * NN;
    float* colpart = q1 + (size_t)BATCH * MM;
    float* rowpart = colpart + (size_t)NBX * BATCH * MM;
    float* colterm = rowpart + (size_t)NBX * BATCH;

    gather_kernel<<<(2 * BATCH * NN) / 256, 256, 0, stream>>>(scores, gt0, gt1, q0, q1);

    dim3 grid(NBX, BATCH);
    main_kernel<<<grid, 256, 0, stream>>>(scores, q0, q1, colpart, rowpart);

    dim3 rgrid(8, BATCH);
    reduce_cols_kernel<<<rgrid, 256, 0, stream>>>(colpart, q1, colterm);

    final_kernel<<<BATCH, 64, 0, stream>>>(rowpart, colterm, out);
}

// Round 6
// 385.913 us; speedup vs baseline: 1.0478x; 1.0021x over previous
//
#include <hip/hip_runtime.h>
#include <math.h>

// Problem constants (b, n, m) = (16, 2048, 2048); scores is (16, 2049, 2049) fp32.
#define BATCH 16
#define NN 2048
#define MM 2048
#define WW 2049
#define GAMMA 0.5f
#define RPB 16          // rows per block (last block takes 17)
#define NBX 128         // row-chunks per batch

// ws layout (floats):
//   q0      : BATCH*NN                 (32768)
//   q1      : BATCH*MM                 (32768)
//   colpart : NBX*BATCH*MM             (4194304 = 16 MB)
//   rowpart : NBX*BATCH                (2048)
//   colterm : BATCH*8                  (128)

// --- Kernel 1: gather q0[b,i] = scores[b,i,gt0[b,i]] - GAMMA,
//               q1[b,j] = scores[b,gt1[b,j],j] - GAMMA.
// max(s-q+GAMMA,0) = max(s,q) - q with q = pos - GAMMA; the -2049*q correction
// is applied once per row/column at the log step.
__global__ __launch_bounds__(256) void gather_kernel(
    const float* __restrict__ scores, const int* __restrict__ gt0,
    const int* __restrict__ gt1, float* __restrict__ q0, float* __restrict__ q1)
{
    int id = blockIdx.x * 256 + threadIdx.x;
    const int half = BATCH * NN;
    if (id < half) {
        int b = id >> 11, i = id & (NN - 1);
        int g = gt0[id];
        g = (g == -1) ? MM : g;
        g = min(max(g, 0), MM);
        q0[id] = scores[(size_t)b * WW * WW + (size_t)i * WW + g] - GAMMA;
    } else {
        int id2 = id - half;
        int b = id2 >> 11, j = id2 & (MM - 1);
        int g = gt1[id2];
        g = (g == -1) ? NN : g;
        g = min(max(g, 0), NN);
        q1[id2] = scores[(size_t)b * WW * WW + (size_t)g * WW + j] - GAMMA;
    }
}

// --- Kernel 2: single pass. Each wave owns a 512-column window of a 16-row
// chunk; lane l covers columns 512*wave + l + 64k, k=0..7. Low register
// pressure (s[8]/q1v[8]/colacc[8]) + explicit 8-load staging keeps 8 loads in
// flight per wave at 32 waves/CU -> 64 KB in flight per CU (latency-BW product
// needs ~9 KB). Row sums close per row via 6-shfl reduce into LDS; logf at end.
__global__ __launch_bounds__(256) void main_kernel(
    const float* __restrict__ scores, const float* __restrict__ q0,
    const float* __restrict__ q1, float* __restrict__ colpart,
    float* __restrict__ rowpart)
{
    const int b = blockIdx.y;
    const int bx = blockIdx.x;
    const int row0 = bx * RPB;
    const int nrows = (bx == NBX - 1) ? (RPB + 1) : RPB;   // fold row 2048
    const int tid = threadIdx.x;
    const int wave = tid >> 6;
    const int lane = tid & 63;
    const int col0 = 512 * wave + lane;                    // + 64*k, k=0..7

    const float* sb = scores + (size_t)b * WW * WW;
    const float* q0b = q0 + b * NN;
    const float* q1b = q1 + b * MM;

    float q1v[8], colacc[8];
#pragma unroll
    for (int k = 0; k < 8; ++k) { q1v[k] = q1b[col0 + 64 * k]; colacc[k] = 0.0f; }

    __shared__ float part[4][RPB + 1];

    const float* rowp = sb + (size_t)row0 * WW + col0;
    for (int r = 0; r < nrows; ++r) {
        const int i = row0 + r;
        const bool has_row = (i < NN);                     // i==2048: col-only
        const float q0i = has_row ? q0b[i] : 0.0f;

        float s[8];
#pragma unroll
        for (int k = 0; k < 8; ++k) s[k] = rowp[64 * k];   // one base + imm offs

        float t = 0.0f;
#pragma unroll
        for (int k = 0; k < 8; ++k) {
            t += fmaxf(s[k], q0i);                         // row contribution
            colacc[k] += fmaxf(s[k], q1v[k]);              // col contribution
        }
        if (wave == 0 && lane == 0)                        // j==2048 (row-only)
            t += fmaxf(sb[(size_t)i * WW + 2048], q0i);
#pragma unroll
        for (int off = 32; off; off >>= 1)
            t += __shfl_xor(t, off);
        if (lane == 0) part[wave][r] = t;
        rowp += WW;
    }
    __syncthreads();

    // Row terms: wave 0, lane r handles row row0+r.
    if (wave == 0) {
        float term = 0.0f;
        if (lane < nrows) {
            const int i = row0 + lane;
            if (i < NN) {
                const float rs = part[0][lane] + part[1][lane]
                               + part[2][lane] + part[3][lane];
                term = 2.0f * logf(rs - 2049.0f * q0b[i] + 0.5f);
            }
        }
#pragma unroll
        for (int off = 32; off; off >>= 1)
            term += __shfl_xor(term, off);
        if (lane == 0) rowpart[bx * BATCH + b] = term;
    }

    // Column partials: plain coalesced stores to this block's private slice.
    float* dst = colpart + ((size_t)bx * BATCH + b) * MM + col0;
#pragma unroll
    for (int k = 0; k < 8; ++k) dst[64 * k] = colacc[k];
}

// --- Kernel 3: per-(b, 256-col chunk) reduce of the 128 block partials, then
// the log term, block-reduced into colterm[b*8 + jc]. Grid (8, 16), 256 thr.
__global__ __launch_bounds__(256) void reduce_cols_kernel(
    const float* __restrict__ colpart, const float* __restrict__ q1,
    float* __restrict__ colterm)
{
    const int b = blockIdx.y;
    const int j = blockIdx.x * 256 + threadIdx.x;
    const int tid = threadIdx.x;
    const int wave = tid >> 6;
    const int lane = tid & 63;

    float s0 = 0.0f, s1 = 0.0f, s2 = 0.0f, s3 = 0.0f;
#pragma unroll 8
    for (int bx = 0; bx < NBX; bx += 4) {
        s0 += colpart[((size_t)(bx + 0) * BATCH + b) * MM + j];
        s1 += colpart[((size_t)(bx + 1) * BATCH + b) * MM + j];
        s2 += colpart[((size_t)(bx + 2) * BATCH + b) * MM + j];
        s3 += colpart[((size_t)(bx + 3) * BATCH + b) * MM + j];
    }
    const float cs = (s0 + s1) + (s2 + s3);
    float term = 2.0f * logf(cs - 2049.0f * q1[b * MM + j] + 0.5f);

#pragma unroll
    for (int off = 32; off; off >>= 1)
        term += __shfl_xor(term, off);

    __shared__ float red[4];
    if (lane == 0) red[wave] = term;
    __syncthreads();
    if (tid == 0)
        colterm[b * 8 + blockIdx.x] = red[0] + red[1] + red[2] + red[3];
}

// --- Kernel 4: final combine. 16 blocks x 64 threads.
__global__ __launch_bounds__(64) void final_kernel(
    const float* __restrict__ rowpart, const float* __restrict__ colterm,
    float* __restrict__ out)
{
    const int b = blockIdx.x;
    const int lane = threadIdx.x;

    float rs = rowpart[lane * BATCH + b] + rowpart[(lane + 64) * BATCH + b];
    float cs = (lane < 8) ? colterm[b * 8 + lane] : 0.0f;
#pragma unroll
    for (int off = 32; off; off >>= 1) {
        rs += __shfl_xor(rs, off);
        cs += __shfl_xor(cs, off);
    }
    if (lane == 0)
        out[b] = 0.5f * (rs * (1.0f / NN) + cs * (1.0f / MM));
}

extern "C" void kernel_launch(void* const* d_in, const int* in_sizes, int n_in,
                              void* d_out, int out_size, void* d_ws, size_t ws_size,
                              hipStream_t stream) {
    const int* gt0 = (const int*)d_in[0];
    const int* gt1 = (const int*)d_in[1];
    const float* scores = (const float*)d_in[2];
    float* out = (float*)d_out;

    float* ws = (float*)d_ws;
    float* q0      = ws;
    float* q1      = q0 + (size_t)BATCH * NN;
    float* colpart = q1 + (size_t)BATCH * MM;
    float* rowpart = colpart + (size_t)NBX * BATCH * MM;
    float* colterm = rowpart + (size_t)NBX * BATCH;

    gather_kernel<<<(2 * BATCH * NN) / 256, 256, 0, stream>>>(scores, gt0, gt1, q0, q1);

    dim3 grid(NBX, BATCH);
    main_kernel<<<grid, 256, 0, stream>>>(scores, q0, q1, colpart, rowpart);

    dim3 rgrid(8, BATCH);
    reduce_cols_kernel<<<rgrid, 256, 0, stream>>>(colpart, q1, colterm);

    final_kernel<<<BATCH, 64, 0, stream>>>(rowpart, colterm, out);
}